// Round 1
// baseline (283.450 us; speedup 1.0000x reference)
//
#include <hip/hip_runtime.h>

typedef __bf16 bf16;
typedef __bf16 bf16x4 __attribute__((ext_vector_type(4)));
typedef __bf16 bf16x8 __attribute__((ext_vector_type(8)));
typedef float f32x4 __attribute__((ext_vector_type(4)));

// Problem constants: B=2, S=2048, D=1024, H=16, HD=64
#define S_LEN 2048
#define D_DIM 1024
#define N_HEAD 16
#define HEAD_DIM 64
#define M_TOK 4096          // B*S
#define BH 32               // B*H

// ---------------- cast fp32 -> bf16 (same layout) ----------------
__global__ __launch_bounds__(256) void k_cast(const float* __restrict__ x,
                                              bf16* __restrict__ o, int n) {
  int i = (blockIdx.x * 256 + threadIdx.x) * 4;
  if (i >= n) return;
  float4 v = *(const float4*)(x + i);
  bf16x4 w;
  w[0] = (bf16)v.x; w[1] = (bf16)v.y; w[2] = (bf16)v.z; w[3] = (bf16)v.w;
  *(bf16x4*)(o + i) = w;
}

// ---------------- transpose + cast: W[K][N] fp32 -> Wt[N][K] bf16 ----------------
__global__ __launch_bounds__(256) void k_transpose(const float* __restrict__ W,
                                                   bf16* __restrict__ Wt,
                                                   int K, int N) {
  __shared__ float tile[32][33];
  int nb = blockIdx.x, kb = blockIdx.y;
  int t = threadIdx.x;
  int r = t >> 3, c4 = (t & 7) * 4;
  float4 v = *(const float4*)&W[(kb * 32 + r) * N + nb * 32 + c4];
  tile[r][c4 + 0] = v.x; tile[r][c4 + 1] = v.y;
  tile[r][c4 + 2] = v.z; tile[r][c4 + 3] = v.w;
  __syncthreads();
  bf16x4 o;
  #pragma unroll
  for (int i = 0; i < 4; i++) o[i] = (bf16)tile[c4 + i][r];
  *(bf16x4*)&Wt[(nb * 32 + r) * K + kb * 32 + c4] = o;
}

// ---------------- GEMM1: qkv = x @ W_attn + b_attn ----------------
// A [4096,1024] bf16, Bt [3072,1024] bf16 (W^T). Writes:
//   q (n<1024):    qk[bh][s][hd] scaled by 0.125   (bh = b*16+h)
//   k (1024..2047): qk + 32*S*HD, same layout
//   v (2048..3071): vT[bh][hd][s]   (transposed for attention B-operand)
__global__ __launch_bounds__(256, 2)
void k_gemm_qkv(const bf16* __restrict__ A, const bf16* __restrict__ Bt,
                const float* __restrict__ bias,
                bf16* __restrict__ qk, bf16* __restrict__ vT) {
  __shared__ bf16 As[128][40];
  __shared__ bf16 Bs[128][40];
  const int K = 1024;
  int bn = blockIdx.x, bm = blockIdx.y;
  int t = threadIdx.x;
  int wave = t >> 6, lane = t & 63, c = lane & 15, quad = lane >> 4;
  int wm = wave & 1, wn = wave >> 1;
  int sr = t >> 2, koff = (t & 3) * 8;

  const bf16* Ag = A + (bm * 128 + sr) * K + koff;
  const bf16* Bg = Bt + (bn * 128 + sr) * K + koff;

  f32x4 acc[4][4] = {};

  for (int k0 = 0; k0 < K; k0 += 32) {
    *(bf16x8*)&As[sr][koff]      = *(const bf16x8*)(Ag + k0);
    *(bf16x8*)&As[sr + 64][koff] = *(const bf16x8*)(Ag + 64 * K + k0);
    *(bf16x8*)&Bs[sr][koff]      = *(const bf16x8*)(Bg + k0);
    *(bf16x8*)&Bs[sr + 64][koff] = *(const bf16x8*)(Bg + 64 * K + k0);
    __syncthreads();
    bf16x8 af[4];
    #pragma unroll
    for (int mt = 0; mt < 4; mt++)
      af[mt] = *(const bf16x8*)&As[wm * 64 + mt * 16 + c][quad * 8];
    #pragma unroll
    for (int nt = 0; nt < 4; nt++) {
      bf16x8 bfr = *(const bf16x8*)&Bs[wn * 64 + nt * 16 + c][quad * 8];
      #pragma unroll
      for (int mt = 0; mt < 4; mt++)
        acc[mt][nt] = __builtin_amdgcn_mfma_f32_16x16x32_bf16(af[mt], bfr, acc[mt][nt], 0, 0, 0);
    }
    __syncthreads();
  }

  #pragma unroll
  for (int nt = 0; nt < 4; nt++) {
    int n = bn * 128 + wn * 64 + nt * 16 + c;
    int which = n >> 10, nl = n & 1023;
    int h = nl >> 6, hd = nl & 63;
    float bv = bias[n];
    #pragma unroll
    for (int mt = 0; mt < 4; mt++) {
      #pragma unroll
      for (int r = 0; r < 4; r++) {
        int m = bm * 128 + wm * 64 + mt * 16 + quad * 4 + r;
        int b = m >> 11, s = m & 2047;
        int bh = b * N_HEAD + h;
        float val = acc[mt][nt][r] + bv;
        if (which == 0) {
          qk[(bh * S_LEN + s) * HEAD_DIM + hd] = (bf16)(val * 0.125f);
        } else if (which == 1) {
          qk[BH * S_LEN * HEAD_DIM + (bh * S_LEN + s) * HEAD_DIM + hd] = (bf16)val;
        } else {
          vT[(bh * HEAD_DIM + hd) * S_LEN + s] = (bf16)val;
        }
      }
    }
  }
}

// ---------------- flash attention (causal) ----------------
// grid: (16 q-tiles, 32 bh). Q pre-scaled by 0.125.
__global__ __launch_bounds__(256, 2)
void k_attn(const bf16* __restrict__ qk, const bf16* __restrict__ vT,
            bf16* __restrict__ y) {
  __shared__ bf16 Ks[64][72];    // [kk][d]
  __shared__ bf16 Vs[64][72];    // [d][kk]
  __shared__ bf16 Ps[128][72];   // [q][kk]
  int qi = blockIdx.x, bh = blockIdx.y;
  int t = threadIdx.x, wave = t >> 6, lane = t & 63, c = lane & 15, quad = lane >> 4;
  const bf16* Qg = qk + (size_t)bh * (S_LEN * HEAD_DIM);
  const bf16* Kg = qk + (size_t)(BH + bh) * (S_LEN * HEAD_DIM);
  const bf16* Vg = vT + (size_t)bh * (HEAD_DIM * S_LEN);

  int qrow = qi * 128 + wave * 32;
  bf16x8 qf[2][2];
  #pragma unroll
  for (int qt = 0; qt < 2; qt++)
    #pragma unroll
    for (int ks = 0; ks < 2; ks++)
      qf[qt][ks] = *(const bf16x8*)&Qg[(qrow + qt * 16 + c) * HEAD_DIM + ks * 32 + quad * 8];

  f32x4 acc_o[2][4] = {};
  float m_i[2][4], l_i[2][4];
  #pragma unroll
  for (int qt = 0; qt < 2; qt++)
    #pragma unroll
    for (int r = 0; r < 4; r++) { m_i[qt][r] = -1e30f; l_i[qt][r] = 0.f; }

  int srow = t >> 3, scol = (t & 7) * 8;
  int nkb = 2 * qi + 2;
  for (int kb = 0; kb < nkb; kb++) {
    __syncthreads();
    *(bf16x8*)&Ks[srow][scol]      = *(const bf16x8*)&Kg[(kb * 64 + srow) * HEAD_DIM + scol];
    *(bf16x8*)&Ks[srow + 32][scol] = *(const bf16x8*)&Kg[(kb * 64 + srow + 32) * HEAD_DIM + scol];
    *(bf16x8*)&Vs[srow][scol]      = *(const bf16x8*)&Vg[srow * S_LEN + kb * 64 + scol];
    *(bf16x8*)&Vs[srow + 32][scol] = *(const bf16x8*)&Vg[(srow + 32) * S_LEN + kb * 64 + scol];
    __syncthreads();

    // S = Q K^T  (q pre-scaled)
    bf16x8 kf[4][2];
    #pragma unroll
    for (int kt = 0; kt < 4; kt++)
      #pragma unroll
      for (int ks = 0; ks < 2; ks++)
        kf[kt][ks] = *(const bf16x8*)&Ks[kt * 16 + c][ks * 32 + quad * 8];

    f32x4 sc[2][4];
    #pragma unroll
    for (int qt = 0; qt < 2; qt++)
      #pragma unroll
      for (int kt = 0; kt < 4; kt++) {
        f32x4 z = {};
        z = __builtin_amdgcn_mfma_f32_16x16x32_bf16(qf[qt][0], kf[kt][0], z, 0, 0, 0);
        z = __builtin_amdgcn_mfma_f32_16x16x32_bf16(qf[qt][1], kf[kt][1], z, 0, 0, 0);
        sc[qt][kt] = z;
      }

    bool diag = (kb >= 2 * qi);
    #pragma unroll
    for (int qt = 0; qt < 2; qt++) {
      #pragma unroll
      for (int r = 0; r < 4; r++) {
        int rowg = qrow + qt * 16 + quad * 4 + r;
        if (diag) {
          #pragma unroll
          for (int kt = 0; kt < 4; kt++) {
            int colg = kb * 64 + kt * 16 + c;
            if (colg > rowg) sc[qt][kt][r] = -1e30f;
          }
        }
        float mx = fmaxf(fmaxf(sc[qt][0][r], sc[qt][1][r]),
                         fmaxf(sc[qt][2][r], sc[qt][3][r]));
        #pragma unroll
        for (int off = 1; off < 16; off <<= 1) mx = fmaxf(mx, __shfl_xor(mx, off, 64));
        float mnew = fmaxf(m_i[qt][r], mx);
        float alpha = __expf(m_i[qt][r] - mnew);
        float sum = 0.f;
        #pragma unroll
        for (int kt = 0; kt < 4; kt++) {
          float p = __expf(sc[qt][kt][r] - mnew);
          sum += p;
          Ps[wave * 32 + qt * 16 + quad * 4 + r][kt * 16 + c] = (bf16)p;
        }
        #pragma unroll
        for (int off = 1; off < 16; off <<= 1) sum += __shfl_xor(sum, off, 64);
        l_i[qt][r] = l_i[qt][r] * alpha + sum;
        m_i[qt][r] = mnew;
        #pragma unroll
        for (int dt = 0; dt < 4; dt++) acc_o[qt][dt][r] *= alpha;
      }
    }
    __syncthreads();

    // O += P V   (P: A-operand from LDS, V: B-operand from Vs[d][kk])
    #pragma unroll
    for (int ks = 0; ks < 2; ks++) {
      bf16x8 pf[2];
      #pragma unroll
      for (int qt = 0; qt < 2; qt++)
        pf[qt] = *(const bf16x8*)&Ps[wave * 32 + qt * 16 + c][ks * 32 + quad * 8];
      #pragma unroll
      for (int dt = 0; dt < 4; dt++) {
        bf16x8 vf = *(const bf16x8*)&Vs[dt * 16 + c][ks * 32 + quad * 8];
        #pragma unroll
        for (int qt = 0; qt < 2; qt++)
          acc_o[qt][dt] = __builtin_amdgcn_mfma_f32_16x16x32_bf16(pf[qt], vf, acc_o[qt][dt], 0, 0, 0);
      }
    }
  }

  int b = bh >> 4, h = bh & 15;
  #pragma unroll
  for (int qt = 0; qt < 2; qt++) {
    #pragma unroll
    for (int r = 0; r < 4; r++) {
      int s = qrow + qt * 16 + quad * 4 + r;
      float inv = 1.0f / l_i[qt][r];
      #pragma unroll
      for (int dt = 0; dt < 4; dt++)
        y[((b * S_LEN + s) * N_HEAD + h) * HEAD_DIM + dt * 16 + c] =
            (bf16)(acc_o[qt][dt][r] * inv);
    }
  }
}

// ---------------- GEMM2: out = y @ W_proj + b_proj (fp32 out) ----------------
__global__ __launch_bounds__(256, 2)
void k_gemm_proj(const bf16* __restrict__ A, const bf16* __restrict__ Bt,
                 const float* __restrict__ bias, float* __restrict__ out) {
  __shared__ bf16 As[128][40];
  __shared__ bf16 Bs[128][40];
  const int K = 1024;
  int bn = blockIdx.x, bm = blockIdx.y;
  int t = threadIdx.x;
  int wave = t >> 6, lane = t & 63, c = lane & 15, quad = lane >> 4;
  int wm = wave & 1, wn = wave >> 1;
  int sr = t >> 2, koff = (t & 3) * 8;

  const bf16* Ag = A + (bm * 128 + sr) * K + koff;
  const bf16* Bg = Bt + (bn * 128 + sr) * K + koff;

  f32x4 acc[4][4] = {};

  for (int k0 = 0; k0 < K; k0 += 32) {
    *(bf16x8*)&As[sr][koff]      = *(const bf16x8*)(Ag + k0);
    *(bf16x8*)&As[sr + 64][koff] = *(const bf16x8*)(Ag + 64 * K + k0);
    *(bf16x8*)&Bs[sr][koff]      = *(const bf16x8*)(Bg + k0);
    *(bf16x8*)&Bs[sr + 64][koff] = *(const bf16x8*)(Bg + 64 * K + k0);
    __syncthreads();
    bf16x8 af[4];
    #pragma unroll
    for (int mt = 0; mt < 4; mt++)
      af[mt] = *(const bf16x8*)&As[wm * 64 + mt * 16 + c][quad * 8];
    #pragma unroll
    for (int nt = 0; nt < 4; nt++) {
      bf16x8 bfr = *(const bf16x8*)&Bs[wn * 64 + nt * 16 + c][quad * 8];
      #pragma unroll
      for (int mt = 0; mt < 4; mt++)
        acc[mt][nt] = __builtin_amdgcn_mfma_f32_16x16x32_bf16(af[mt], bfr, acc[mt][nt], 0, 0, 0);
    }
    __syncthreads();
  }

  #pragma unroll
  for (int nt = 0; nt < 4; nt++) {
    int n = bn * 128 + wn * 64 + nt * 16 + c;
    float bv = bias[n];
    #pragma unroll
    for (int mt = 0; mt < 4; mt++) {
      #pragma unroll
      for (int r = 0; r < 4; r++) {
        int m = bm * 128 + wm * 64 + mt * 16 + quad * 4 + r;
        out[m * D_DIM + n] = acc[mt][nt][r] + bv;
      }
    }
  }
}

extern "C" void kernel_launch(void* const* d_in, const int* in_sizes, int n_in,
                              void* d_out, int out_size, void* d_ws, size_t ws_size,
                              hipStream_t stream) {
  const float* x      = (const float*)d_in[0];
  const float* W_attn = (const float*)d_in[1];
  const float* b_attn = (const float*)d_in[2];
  const float* W_proj = (const float*)d_in[3];
  const float* b_proj = (const float*)d_in[4];
  float* out = (float*)d_out;

  bf16* x_bf = (bf16*)d_ws;                       // 4M elems
  bf16* wat  = x_bf + 4096 * 1024;                // 3M
  bf16* wpt  = wat + 3072 * 1024;                 // 1M
  bf16* qk   = wpt + 1024 * 1024;                 // 8M (q then k)
  bf16* vT   = qk + 8 * 1024 * 1024;              // 4M
  bf16* y_bf = vT + 4 * 1024 * 1024;              // 4M  (total 48MB)

  k_cast<<<4096, 256, 0, stream>>>(x, x_bf, 4096 * 1024);
  k_transpose<<<dim3(3072 / 32, 1024 / 32), 256, 0, stream>>>(W_attn, wat, 1024, 3072);
  k_transpose<<<dim3(1024 / 32, 1024 / 32), 256, 0, stream>>>(W_proj, wpt, 1024, 1024);
  k_gemm_qkv<<<dim3(24, 32), 256, 0, stream>>>(x_bf, wat, b_attn, qk, vT);
  k_attn<<<dim3(16, 32), 256, 0, stream>>>(qk, vT, y_bf);
  k_gemm_proj<<<dim3(8, 32), 256, 0, stream>>>(y_bf, wpt, b_proj, out);
}

// Round 2
// 193.974 us; speedup vs baseline: 1.4613x; 1.4613x over previous
//
#include <hip/hip_runtime.h>

typedef __bf16 bf16;
typedef __bf16 bf16x4 __attribute__((ext_vector_type(4)));
typedef __bf16 bf16x8 __attribute__((ext_vector_type(8)));
typedef float f32x4 __attribute__((ext_vector_type(4)));

#define S_LEN 2048
#define D_DIM 1024
#define N_HEAD 16
#define HEAD_DIM 64
#define M_TOK 4096
#define BH 32

#define EXP2F(x) __builtin_amdgcn_exp2f(x)
// 1/sqrt(64) * log2(e)
#define Q_SCALE 0.18033688f

typedef __attribute__((address_space(3))) void lds_void;
typedef const __attribute__((address_space(1))) void gbl_void;

__device__ __forceinline__ void gl_lds16(const bf16* g, bf16* l) {
  __builtin_amdgcn_global_load_lds((gbl_void*)g, (lds_void*)l, 16, 0, 0);
}

// ---------------- cast fp32 -> bf16 ----------------
__global__ __launch_bounds__(256) void k_cast(const float* __restrict__ x,
                                              bf16* __restrict__ o, int n) {
  int i = (blockIdx.x * 256 + threadIdx.x) * 4;
  if (i >= n) return;
  float4 v = *(const float4*)(x + i);
  bf16x4 w;
  w[0] = (bf16)v.x; w[1] = (bf16)v.y; w[2] = (bf16)v.z; w[3] = (bf16)v.w;
  *(bf16x4*)(o + i) = w;
}

// ---------------- transpose+cast: W[K][N] fp32 -> Wt[N][K] bf16 ----------------
__global__ __launch_bounds__(256) void k_transpose(const float* __restrict__ W,
                                                   bf16* __restrict__ Wt,
                                                   int K, int N) {
  __shared__ float tile[32][33];
  int nb = blockIdx.x, kb = blockIdx.y;
  int t = threadIdx.x;
  int r = t >> 3, c4 = (t & 7) * 4;
  float4 v = *(const float4*)&W[(kb * 32 + r) * N + nb * 32 + c4];
  tile[r][c4 + 0] = v.x; tile[r][c4 + 1] = v.y;
  tile[r][c4 + 2] = v.z; tile[r][c4 + 3] = v.w;
  __syncthreads();
  bf16x4 o;
  #pragma unroll
  for (int i = 0; i < 4; i++) o[i] = (bf16)tile[c4 + i][r];
  *(bf16x4*)&Wt[(nb * 32 + r) * K + kb * 32 + c4] = o;
}

// ---------------- GEMM1: qkv = x @ W_attn + b_attn (global_load_lds staging) ----------------
__global__ __launch_bounds__(256, 2)
void k_gemm_qkv(const bf16* __restrict__ A, const bf16* __restrict__ Bt,
                const float* __restrict__ bias,
                bf16* __restrict__ qk, bf16* __restrict__ vT) {
  __shared__ bf16 As[128 * 32];
  __shared__ bf16 Bs[128 * 32];
  const int K = 1024;
  int bn = blockIdx.x, bm = blockIdx.y;
  int t = threadIdx.x;
  int wave = t >> 6, lane = t & 63, c = lane & 15, quad = lane >> 4;
  int wm = wave & 1, wn = wave >> 1;
  int ldrow = lane >> 2, ldcol = (lane & 3) * 8;

  const bf16* Ag = A + (size_t)(bm * 128) * K;
  const bf16* Bg = Bt + (size_t)(bn * 128) * K;

  f32x4 acc[4][4] = {};

  for (int k0 = 0; k0 < K; k0 += 32) {
    __syncthreads();
    #pragma unroll
    for (int q = 0; q < 2; q++) {
      int r0 = (wave * 2 + q) * 16;
      gl_lds16(&Ag[(size_t)(r0 + ldrow) * K + k0 + ldcol], &As[r0 * 32]);
      gl_lds16(&Bg[(size_t)(r0 + ldrow) * K + k0 + ldcol], &Bs[r0 * 32]);
    }
    __syncthreads();
    bf16x8 af[4];
    #pragma unroll
    for (int mt = 0; mt < 4; mt++)
      af[mt] = *(const bf16x8*)&As[(wm * 64 + mt * 16 + c) * 32 + quad * 8];
    #pragma unroll
    for (int nt = 0; nt < 4; nt++) {
      bf16x8 bfr = *(const bf16x8*)&Bs[(wn * 64 + nt * 16 + c) * 32 + quad * 8];
      #pragma unroll
      for (int mt = 0; mt < 4; mt++)
        acc[mt][nt] = __builtin_amdgcn_mfma_f32_16x16x32_bf16(af[mt], bfr, acc[mt][nt], 0, 0, 0);
    }
  }

  #pragma unroll
  for (int nt = 0; nt < 4; nt++) {
    int n = bn * 128 + wn * 64 + nt * 16 + c;
    int which = n >> 10, nl = n & 1023;
    int h = nl >> 6, hd = nl & 63;
    float bv = bias[n];
    #pragma unroll
    for (int mt = 0; mt < 4; mt++) {
      #pragma unroll
      for (int r = 0; r < 4; r++) {
        int m = bm * 128 + wm * 64 + mt * 16 + quad * 4 + r;
        int b = m >> 11, s = m & 2047;
        int bh = b * N_HEAD + h;
        float val = acc[mt][nt][r] + bv;
        if (which == 0) {
          qk[(bh * S_LEN + s) * HEAD_DIM + hd] = (bf16)(val * Q_SCALE);
        } else if (which == 1) {
          qk[BH * S_LEN * HEAD_DIM + (bh * S_LEN + s) * HEAD_DIM + hd] = (bf16)val;
        } else {
          vT[((size_t)bh * HEAD_DIM + hd) * S_LEN + s] = (bf16)val;
        }
      }
    }
  }
}

// ---------------- flash attention (causal), balanced pairs, S^T/O^T layout ----------------
// 64-row q-tiles (32 total); block p handles tiles {p, 31-p}: uniform 33 k-iters.
__global__ __launch_bounds__(256, 2)
void k_attn(const bf16* __restrict__ qk, const bf16* __restrict__ vT,
            bf16* __restrict__ y) {
  __shared__ bf16 Ks[64][72];    // [kpos][d]
  __shared__ bf16 Vs[64][72];    // [d][kpos]
  __shared__ bf16 Ps[64][72];    // [q][kpos]
  int p = blockIdx.x, bh = blockIdx.y;
  int t = threadIdx.x, w = t >> 6, lane = t & 63, c = lane & 15, quad = lane >> 4;
  const bf16* Qg = qk + (size_t)bh * (S_LEN * HEAD_DIM);
  const bf16* Kg = qk + (size_t)(BH + bh) * (S_LEN * HEAD_DIM);
  const bf16* Vg = vT + (size_t)bh * (HEAD_DIM * S_LEN);
  int b = bh >> 4, h = bh & 15;
  int srow = t >> 3;           // 0..31
  int scol = (t & 7) * 8;      // 0..56

  #pragma unroll
  for (int phase = 0; phase < 2; phase++) {
    int tile = (phase == 0) ? p : 31 - p;
    int nkb = tile + 1;
    int qrow = tile * 64 + w * 16;

    bf16x8 qf[2];
    qf[0] = *(const bf16x8*)&Qg[(qrow + c) * HEAD_DIM + quad * 8];
    qf[1] = *(const bf16x8*)&Qg[(qrow + c) * HEAD_DIM + 32 + quad * 8];

    float m = -1e30f, l = 0.f;
    f32x4 acc[4] = {};   // O^T: acc[dt][r] -> (d = dt*16+quad*4+r, q = c)

    bf16x8 kr0, kr1, vr0, vr1;
    kr0 = *(const bf16x8*)&Kg[(0 * 64 + srow) * HEAD_DIM + scol];
    kr1 = *(const bf16x8*)&Kg[(0 * 64 + srow + 32) * HEAD_DIM + scol];
    vr0 = *(const bf16x8*)&Vg[(size_t)srow * S_LEN + 0 * 64 + scol];
    vr1 = *(const bf16x8*)&Vg[(size_t)(srow + 32) * S_LEN + 0 * 64 + scol];

    for (int kb = 0; kb < nkb; kb++) {
      __syncthreads();
      *(bf16x8*)&Ks[srow][scol] = kr0;
      *(bf16x8*)&Ks[srow + 32][scol] = kr1;
      *(bf16x8*)&Vs[srow][scol] = vr0;
      *(bf16x8*)&Vs[srow + 32][scol] = vr1;
      __syncthreads();
      if (kb + 1 < nkb) {   // prefetch next K/V block (overlaps compute)
        kr0 = *(const bf16x8*)&Kg[((kb + 1) * 64 + srow) * HEAD_DIM + scol];
        kr1 = *(const bf16x8*)&Kg[((kb + 1) * 64 + srow + 32) * HEAD_DIM + scol];
        vr0 = *(const bf16x8*)&Vg[(size_t)srow * S_LEN + (kb + 1) * 64 + scol];
        vr1 = *(const bf16x8*)&Vg[(size_t)(srow + 32) * S_LEN + (kb + 1) * 64 + scol];
      }

      // S^T = K Q^T : per kt tile lane holds (kpos = kt*16+quad*4+r, q = c)
      f32x4 sc[4];
      #pragma unroll
      for (int kt = 0; kt < 4; kt++) {
        bf16x8 kf0 = *(const bf16x8*)&Ks[kt * 16 + c][quad * 8];
        bf16x8 kf1 = *(const bf16x8*)&Ks[kt * 16 + c][32 + quad * 8];
        f32x4 z = {};
        z = __builtin_amdgcn_mfma_f32_16x16x32_bf16(kf0, qf[0], z, 0, 0, 0);
        z = __builtin_amdgcn_mfma_f32_16x16x32_bf16(kf1, qf[1], z, 0, 0, 0);
        sc[kt] = z;
      }

      if (kb == tile) {  // diagonal block: mask kpos > q
        #pragma unroll
        for (int kt = 0; kt < 4; kt++)
          #pragma unroll
          for (int r = 0; r < 4; r++)
            if (kt * 16 + quad * 4 + r > w * 16 + c) sc[kt][r] = -1e30f;
      }

      // online softmax over this lane's q-row (q = c); scores in log2 domain
      float mx = sc[0][0];
      #pragma unroll
      for (int kt = 0; kt < 4; kt++)
        #pragma unroll
        for (int r = 0; r < 4; r++) mx = fmaxf(mx, sc[kt][r]);
      mx = fmaxf(mx, __shfl_xor(mx, 16));
      mx = fmaxf(mx, __shfl_xor(mx, 32));
      float mnew = fmaxf(m, mx);
      float alpha = EXP2F(m - mnew);
      float sum = 0.f;
      #pragma unroll
      for (int kt = 0; kt < 4; kt++) {
        bf16x4 pk;
        #pragma unroll
        for (int r = 0; r < 4; r++) {
          float pv = EXP2F(sc[kt][r] - mnew);
          sum += pv;
          pk[r] = (bf16)pv;
        }
        *(bf16x4*)&Ps[w * 16 + c][kt * 16 + quad * 4] = pk;
      }
      sum += __shfl_xor(sum, 16);
      sum += __shfl_xor(sum, 32);
      l = l * alpha + sum;
      m = mnew;
      #pragma unroll
      for (int dt = 0; dt < 4; dt++)
        #pragma unroll
        for (int r = 0; r < 4; r++) acc[dt][r] *= alpha;

      // O^T += V^T P^T  (A = Vs[d][kk], B = Ps[q][kk]; own wave's Ps rows only)
      #pragma unroll
      for (int ks = 0; ks < 2; ks++) {
        bf16x8 pf = *(const bf16x8*)&Ps[w * 16 + c][ks * 32 + quad * 8];
        #pragma unroll
        for (int dt = 0; dt < 4; dt++) {
          bf16x8 vf = *(const bf16x8*)&Vs[dt * 16 + c][ks * 32 + quad * 8];
          acc[dt] = __builtin_amdgcn_mfma_f32_16x16x32_bf16(vf, pf, acc[dt], 0, 0, 0);
        }
      }
    }

    // epilogue: row q = qrow + c, d = dt*16 + quad*4 + r  -> b64 packed stores
    float linv = 1.0f / l;
    #pragma unroll
    for (int dt = 0; dt < 4; dt++) {
      bf16x4 o;
      #pragma unroll
      for (int r = 0; r < 4; r++) o[r] = (bf16)(acc[dt][r] * linv);
      *(bf16x4*)&y[((size_t)(b * S_LEN + qrow + c) * N_HEAD + h) * HEAD_DIM + dt * 16 + quad * 4] = o;
    }
  }
}

// ---------------- GEMM2: out = y @ W_proj + b_proj (fp32 out) ----------------
__global__ __launch_bounds__(256, 2)
void k_gemm_proj(const bf16* __restrict__ A, const bf16* __restrict__ Bt,
                 const float* __restrict__ bias, float* __restrict__ out) {
  __shared__ bf16 As[128 * 32];
  __shared__ bf16 Bs[128 * 32];
  const int K = 1024;
  int bn = blockIdx.x, bm = blockIdx.y;
  int t = threadIdx.x;
  int wave = t >> 6, lane = t & 63, c = lane & 15, quad = lane >> 4;
  int wm = wave & 1, wn = wave >> 1;
  int ldrow = lane >> 2, ldcol = (lane & 3) * 8;

  const bf16* Ag = A + (size_t)(bm * 128) * K;
  const bf16* Bg = Bt + (size_t)(bn * 128) * K;

  f32x4 acc[4][4] = {};

  for (int k0 = 0; k0 < K; k0 += 32) {
    __syncthreads();
    #pragma unroll
    for (int q = 0; q < 2; q++) {
      int r0 = (wave * 2 + q) * 16;
      gl_lds16(&Ag[(size_t)(r0 + ldrow) * K + k0 + ldcol], &As[r0 * 32]);
      gl_lds16(&Bg[(size_t)(r0 + ldrow) * K + k0 + ldcol], &Bs[r0 * 32]);
    }
    __syncthreads();
    bf16x8 af[4];
    #pragma unroll
    for (int mt = 0; mt < 4; mt++)
      af[mt] = *(const bf16x8*)&As[(wm * 64 + mt * 16 + c) * 32 + quad * 8];
    #pragma unroll
    for (int nt = 0; nt < 4; nt++) {
      bf16x8 bfr = *(const bf16x8*)&Bs[(wn * 64 + nt * 16 + c) * 32 + quad * 8];
      #pragma unroll
      for (int mt = 0; mt < 4; mt++)
        acc[mt][nt] = __builtin_amdgcn_mfma_f32_16x16x32_bf16(af[mt], bfr, acc[mt][nt], 0, 0, 0);
    }
  }

  #pragma unroll
  for (int nt = 0; nt < 4; nt++) {
    int n = bn * 128 + wn * 64 + nt * 16 + c;
    float bv = bias[n];
    #pragma unroll
    for (int mt = 0; mt < 4; mt++) {
      #pragma unroll
      for (int r = 0; r < 4; r++) {
        int m = bm * 128 + wm * 64 + mt * 16 + quad * 4 + r;
        out[(size_t)m * D_DIM + n] = acc[mt][nt][r] + bv;
      }
    }
  }
}

extern "C" void kernel_launch(void* const* d_in, const int* in_sizes, int n_in,
                              void* d_out, int out_size, void* d_ws, size_t ws_size,
                              hipStream_t stream) {
  const float* x      = (const float*)d_in[0];
  const float* W_attn = (const float*)d_in[1];
  const float* b_attn = (const float*)d_in[2];
  const float* W_proj = (const float*)d_in[3];
  const float* b_proj = (const float*)d_in[4];
  float* out = (float*)d_out;

  bf16* x_bf = (bf16*)d_ws;
  bf16* wat  = x_bf + 4096 * 1024;
  bf16* wpt  = wat + 3072 * 1024;
  bf16* qk   = wpt + 1024 * 1024;
  bf16* vT   = qk + 8 * 1024 * 1024;
  bf16* y_bf = vT + 4 * 1024 * 1024;

  k_cast<<<4096, 256, 0, stream>>>(x, x_bf, 4096 * 1024);
  k_transpose<<<dim3(3072 / 32, 1024 / 32), 256, 0, stream>>>(W_attn, wat, 1024, 3072);
  k_transpose<<<dim3(1024 / 32, 1024 / 32), 256, 0, stream>>>(W_proj, wpt, 1024, 1024);
  k_gemm_qkv<<<dim3(24, 32), 256, 0, stream>>>(x_bf, wat, b_attn, qk, vT);
  k_attn<<<dim3(16, 32), 256, 0, stream>>>(qk, vT, y_bf);
  k_gemm_proj<<<dim3(8, 32), 256, 0, stream>>>(y_bf, wpt, b_proj, out);
}